// Round 8
// baseline (110.694 us; speedup 1.0000x reference)
//
#include <hip/hip_runtime.h>
#include <math.h>

#define BB 4
#define SS 16384
#define NN 1024
#define DD 64
#define MW 32    // bitmap words per row = NN/32
#define RPB 8    // rows per block (512 blocks total)
#define FCAP 192 // per-row flow-list capacity; Poisson(16) => P(>192) ~ 0
#define JCAP 256 // compact neighbor-list capacity; P(degree>256) ~ 0

__device__ __forceinline__ float wave_sum(float v) {
    #pragma unroll
    for (int off = 32; off > 0; off >>= 1) v += __shfl_xor(v, off, 64);
    return v;
}
__device__ __forceinline__ float wave_max(float v) {
    #pragma unroll
    for (int off = 32; off > 0; off >>= 1) v = fmaxf(v, __shfl_xor(v, off, 64));
    return v;
}

// Kernel A: block = 8 consecutive rows of one batch. Scan the batch's dst_ips
// (int4) to build per-row flow lists in LDS, then per wave (2 rows each):
// float4 gather-sum of ff rows, normalize, h@W, f1, f2. Writes every row of
// Wh/f1/f2 -> no global zero-init needed anywhere in the pipeline.
__global__ __launch_bounds__(256) void gather_transform_scan(
        const float* __restrict__ ff, const int* __restrict__ dst_ips,
        const float* __restrict__ W, const float* __restrict__ a1,
        const float* __restrict__ a2, float* __restrict__ Wh,
        float* __restrict__ f1, float* __restrict__ f2) {
    __shared__ float Ws[DD * DD];
    __shared__ float a1s[DD], a2s[DD];
    __shared__ float hs[4][DD];
    __shared__ int lcnt[RPB];
    __shared__ int lst[RPB][FCAP];
    int t = threadIdx.x;
    for (int i = t; i < DD * DD / 4; i += 256)
        ((float4*)Ws)[i] = ((const float4*)W)[i];
    if (t < DD) { a1s[t] = a1[t]; a2s[t] = a2[t]; }
    if (t < RPB) lcnt[t] = 0;
    __syncthreads();

    int blk = blockIdx.x;
    int b = blk >> 7;                           // 128 blocks per batch
    int n0 = (blk & 127) * RPB;                 // first node of this block
    const int* db = dst_ips + b * SS;

    // scan: 16 iterations of one int4 load per thread
    for (int f4 = t; f4 < SS / 4; f4 += 256) {
        int4 d = ((const int4*)db)[f4];
        int f = f4 << 2;
        #define CHK(c, off) { unsigned r = (unsigned)(c - n0); \
            if (r < RPB) { int p = atomicAdd(&lcnt[r], 1); \
                           if (p < FCAP) lst[r][p] = f + off; } }
        CHK(d.x, 0) CHK(d.y, 1) CHK(d.z, 2) CHK(d.w, 3)
        #undef CHK
    }
    __syncthreads();

    int wave = t >> 6, lane = t & 63;
    int fq = lane >> 4;                         // flow slot 0..3
    int qi = lane & 15;                         // float4 index within row
    const float* ffb = ff + (size_t)b * SS * DD;

    for (int rr = 0; rr < 2; ++rr) {
        int lr = wave * 2 + rr;                 // 0..7
        int row = blk * RPB + lr;               // [0, BB*NN)
        int cnt = min(lcnt[lr], FCAP);
        float4 v0 = make_float4(0.f, 0.f, 0.f, 0.f);
        float4 v1 = make_float4(0.f, 0.f, 0.f, 0.f);
        for (int k = fq; k < cnt; k += 8) {
            int F0 = lst[lr][k];
            float4 x = ((const float4*)(ffb + (size_t)F0 * DD))[qi];
            v0.x += x.x; v0.y += x.y; v0.z += x.z; v0.w += x.w;
            int k1 = k + 4;
            if (k1 < cnt) {
                int F1 = lst[lr][k1];
                float4 y = ((const float4*)(ffb + (size_t)F1 * DD))[qi];
                v1.x += y.x; v1.y += y.y; v1.z += y.z; v1.w += y.w;
            }
        }
        float4 v = make_float4(v0.x + v1.x, v0.y + v1.y,
                               v0.z + v1.z, v0.w + v1.w);
        #pragma unroll
        for (int off = 16; off <= 32; off <<= 1) {
            v.x += __shfl_xor(v.x, off, 64);
            v.y += __shfl_xor(v.y, off, 64);
            v.z += __shfl_xor(v.z, off, 64);
            v.w += __shfl_xor(v.w, off, 64);
        }
        float ssq = (fq == 0) ? (v.x*v.x + v.y*v.y + v.z*v.z + v.w*v.w) : 0.f;
        float nrm = fmaxf(sqrtf(wave_sum(ssq)), 1e-12f);
        float inv = 1.f / nrm;
        if (fq == 0)
            ((float4*)hs[wave])[qi] =
                make_float4(v.x*inv, v.y*inv, v.z*inv, v.w*inv);
        // same-wave LDS write->read: DS ops program-ordered, no barrier
        float whl = 0.f;
        #pragma unroll
        for (int k = 0; k < DD; ++k)
            whl = fmaf(hs[wave][k], Ws[k * DD + lane], whl);
        Wh[(size_t)row * DD + lane] = whl;
        float p1 = wave_sum(whl * a1s[lane]);
        float p2 = wave_sum(whl * a2s[lane]);
        if (lane == 0) { f1[row] = p1; f2[row] = p2; }
    }
}

// Kernel B: block = 8 consecutive rows of one batch. Scan src+dst (int4) to
// build per-row neighbor bitmaps in LDS (symmetric adjacency), then per wave
// (2 rows): compact ascending, softmax over neighbors, float4 x2 accumulation.
__global__ __launch_bounds__(256) void attn_scan(
        const int* __restrict__ src_ips, const int* __restrict__ dst_ips,
        const float* __restrict__ f1, const float* __restrict__ f2,
        const float* __restrict__ Wh, float* __restrict__ out) {
    __shared__ unsigned int bms[RPB][MW];
    __shared__ int   jls[RPB][JCAP];
    __shared__ float pls[RPB][JCAP];
    int t = threadIdx.x;
    bms[t >> 5][t & 31] = 0u;                   // 256 threads = 8*32 words
    __syncthreads();

    int blk = blockIdx.x;
    int b = blk >> 7;
    int n0 = (blk & 127) * RPB;
    const int* db = dst_ips + b * SS;
    const int* sb = src_ips + b * SS;

    for (int f4 = t; f4 < SS / 4; f4 += 256) {
        int4 d = ((const int4*)db)[f4];
        int4 s = ((const int4*)sb)[f4];
        #define CHK(dc, sc) { \
            unsigned r1 = (unsigned)(dc - n0); \
            if (r1 < RPB) atomicOr(&bms[r1][sc >> 5], 1u << (sc & 31)); \
            unsigned r2 = (unsigned)(sc - n0); \
            if (r2 < RPB) atomicOr(&bms[r2][dc >> 5], 1u << (dc & 31)); }
        CHK(d.x, s.x) CHK(d.y, s.y) CHK(d.z, s.z) CHK(d.w, s.w)
        #undef CHK
    }
    __syncthreads();

    int wave = t >> 6, lane = t & 63;
    int fq = lane >> 4;
    int qi = lane & 15;
    const float* f2b = f2 + b * NN;
    const float* Whb = Wh + (size_t)(b << 10) * DD;

    for (int rr = 0; rr < 2; ++rr) {
        int lr = wave * 2 + rr;                 // 0..7, unique per wave
        int row = blk * RPB + lr;
        float f1i = f1[row];
        unsigned int mword = (lane < MW) ? bms[lr][lane] : 0u;

        // compact set bits (ascending j): prefix-sum of per-word popc
        int pc = __popc(mword);
        int x = pc;
        #pragma unroll
        for (int off = 1; off < 64; off <<= 1) {
            int y = __shfl_up(x, off, 64);
            if (lane >= off) x += y;
        }
        int cnt = __shfl(x, 63, 64);
        int o = x - pc;
        if (cnt <= JCAP) {
            unsigned int bits = mword;
            while (bits) {
                int bidx = __ffs(bits) - 1; bits &= bits - 1;
                jls[lr][o++] = (lane << 5) + bidx;
            }
        }

        if (cnt > 0 && cnt <= JCAP) {
            float m = -INFINITY;
            for (int k = lane; k < cnt; k += 64) {
                int j = jls[lr][k];
                float e = f1i + f2b[j];
                e = (e >= 0.f) ? e : 0.2f * e;
                m = fmaxf(m, e);
            }
            m = wave_max(m);
            float lsum = 0.f;
            for (int k = lane; k < cnt; k += 64) {
                int j = jls[lr][k];
                float e = f1i + f2b[j];
                e = (e >= 0.f) ? e : 0.2f * e;
                float p = __expf(e - m);
                pls[lr][k] = p;
                lsum += p;
            }
            lsum = wave_sum(lsum);
            float4 a0 = make_float4(0.f, 0.f, 0.f, 0.f);
            float4 a1v = make_float4(0.f, 0.f, 0.f, 0.f);
            for (int k = fq; k < cnt; k += 8) {
                int j0   = jls[lr][k];
                float p0 = pls[lr][k];
                float4 w0 = ((const float4*)(Whb + (size_t)j0 * DD))[qi];
                a0.x = fmaf(p0, w0.x, a0.x);
                a0.y = fmaf(p0, w0.y, a0.y);
                a0.z = fmaf(p0, w0.z, a0.z);
                a0.w = fmaf(p0, w0.w, a0.w);
                int k1 = k + 4;
                if (k1 < cnt) {
                    int j1   = jls[lr][k1];
                    float p1 = pls[lr][k1];
                    float4 w1 = ((const float4*)(Whb + (size_t)j1 * DD))[qi];
                    a1v.x = fmaf(p1, w1.x, a1v.x);
                    a1v.y = fmaf(p1, w1.y, a1v.y);
                    a1v.z = fmaf(p1, w1.z, a1v.z);
                    a1v.w = fmaf(p1, w1.w, a1v.w);
                }
            }
            float4 acc = make_float4(a0.x + a1v.x, a0.y + a1v.y,
                                     a0.z + a1v.z, a0.w + a1v.w);
            #pragma unroll
            for (int off = 16; off <= 32; off <<= 1) {
                acc.x += __shfl_xor(acc.x, off, 64);
                acc.y += __shfl_xor(acc.y, off, 64);
                acc.z += __shfl_xor(acc.z, off, 64);
                acc.w += __shfl_xor(acc.w, off, 64);
            }
            if (fq == 0) {
                float inv = 1.f / lsum;
                float4 r;
                r.x = acc.x * inv; r.y = acc.y * inv;
                r.z = acc.z * inv; r.w = acc.w * inv;
                r.x = (r.x > 0.f) ? r.x : expm1f(r.x);
                r.y = (r.y > 0.f) ? r.y : expm1f(r.y);
                r.z = (r.z > 0.f) ? r.z : expm1f(r.z);
                r.w = (r.w > 0.f) ? r.w : expm1f(r.w);
                ((float4*)(out + (size_t)row * DD))[qi] = r;
            }
        } else if (cnt == 0) {
            // isolated node: softmax of uniform NEG_BIG = 1/N over ALL j
            float4 acc = make_float4(0.f, 0.f, 0.f, 0.f);
            for (int k = fq; k < NN; k += 4) {
                float4 w = ((const float4*)(Whb + (size_t)k * DD))[qi];
                acc.x += w.x; acc.y += w.y; acc.z += w.z; acc.w += w.w;
            }
            #pragma unroll
            for (int off = 16; off <= 32; off <<= 1) {
                acc.x += __shfl_xor(acc.x, off, 64);
                acc.y += __shfl_xor(acc.y, off, 64);
                acc.z += __shfl_xor(acc.z, off, 64);
                acc.w += __shfl_xor(acc.w, off, 64);
            }
            if (fq == 0) {
                float4 r;
                r.x = acc.x * (1.f / NN); r.y = acc.y * (1.f / NN);
                r.z = acc.z * (1.f / NN); r.w = acc.w * (1.f / NN);
                r.x = (r.x > 0.f) ? r.x : expm1f(r.x);
                r.y = (r.y > 0.f) ? r.y : expm1f(r.y);
                r.z = (r.z > 0.f) ? r.z : expm1f(r.z);
                r.w = (r.w > 0.f) ? r.w : expm1f(r.w);
                ((float4*)(out + (size_t)row * DD))[qi] = r;
            }
        } else {
            // cnt > JCAP: full bitmap-scan fallback (statistically never)
            float m = -INFINITY;
            for (int tt = 0; tt < 16; ++tt) {
                int j = lane + (tt << 6);
                if (bms[lr][j >> 5] & (1u << (j & 31))) {
                    float e = f1i + f2b[j];
                    e = (e >= 0.f) ? e : 0.2f * e;
                    m = fmaxf(m, e);
                }
            }
            m = wave_max(m);
            float lsum = 0.f;
            for (int tt = 0; tt < 16; ++tt) {
                int j = lane + (tt << 6);
                if (bms[lr][j >> 5] & (1u << (j & 31))) {
                    float e = f1i + f2b[j];
                    e = (e >= 0.f) ? e : 0.2f * e;
                    lsum += __expf(e - m);
                }
            }
            lsum = wave_sum(lsum);
            float acc = 0.f;
            for (int w = 0; w < MW; ++w) {
                unsigned int bits = bms[lr][w];
                while (bits) {
                    int j = (w << 5) + (__ffs(bits) - 1);
                    bits &= bits - 1;
                    float e = f1i + f2b[j];
                    e = (e >= 0.f) ? e : 0.2f * e;
                    acc = fmaf(__expf(e - m), Whb[(size_t)j * DD + lane], acc);
                }
            }
            acc /= lsum;
            out[(size_t)row * DD + lane] = (acc > 0.f) ? acc : expm1f(acc);
        }
    }
}

extern "C" void kernel_launch(void* const* d_in, const int* in_sizes, int n_in,
                              void* d_out, int out_size, void* d_ws, size_t ws_size,
                              hipStream_t stream) {
    const float* ff      = (const float*)d_in[0];
    const int*   src_ips = (const int*)d_in[1];
    const int*   dst_ips = (const int*)d_in[2];
    // d_in[3] flow_volumes, d_in[4] emb, d_in[5..8] MLP params: adj weights are
    // products of sigmoids => strictly positive => only the >0 mask matters.
    const float* W  = (const float*)d_in[9];
    const float* a1 = (const float*)d_in[10];
    const float* a2 = (const float*)d_in[11];
    float* out = (float*)d_out;

    char* ws = (char*)d_ws;
    float* Wh = (float*)ws;                         // 1 MB
    float* f1 = (float*)(ws + (1 << 20));           // 16 KB
    float* f2 = (float*)(ws + (1 << 20) + (16 << 10)); // 16 KB
    // No memset: kernel A writes every element of Wh/f1/f2 unconditionally.

    gather_transform_scan<<<BB * NN / RPB, 256, 0, stream>>>(
        ff, dst_ips, W, a1, a2, Wh, f1, f2);
    attn_scan<<<BB * NN / RPB, 256, 0, stream>>>(
        src_ips, dst_ips, f1, f2, Wh, out);
}

// Round 9
// 104.469 us; speedup vs baseline: 1.0596x; 1.0596x over previous
//
#include <hip/hip_runtime.h>
#include <math.h>

#define BB 4
#define SS 16384
#define NN 1024
#define DD 64
#define MW 32    // bitmap words per row = NN/32
#define CAP 256  // bucket capacity per (b,node); Poisson(16) => overflow P ~ 0
#define JCAP 512 // compact neighbor-list capacity; union of two CAP lists <= 512

__device__ __forceinline__ float wave_sum(float v) {
    #pragma unroll
    for (int off = 32; off > 0; off >>= 1) v += __shfl_xor(v, off, 64);
    return v;
}
__device__ __forceinline__ float wave_max(float v) {
    #pragma unroll
    for (int off = 32; off > 0; off >>= 1) v = fmaxf(v, __shfl_xor(v, off, 64));
    return v;
}

// 1 thread per flow: dual CSR buckets. bucket_d keyed by (b,dst) stores
// tid|src<<16 (tid<65536, src<1024); bucket_s keyed by (b,src) stores dst.
// 2 atomics/flow; no scattered global atomicOr.
__global__ __launch_bounds__(256) void build_kernel(
        const int* __restrict__ src_ips, const int* __restrict__ dst_ips,
        int* __restrict__ cntd, int* __restrict__ cnts,
        int* __restrict__ bucket_d, int* __restrict__ bucket_s) {
    int tid = blockIdx.x * 256 + threadIdx.x;   // global flow id, [0, BB*SS)
    int b   = tid >> 14;                        // SS = 2^14
    int dst = dst_ips[tid];
    int src = src_ips[tid];
    int rd = (b << 10) + dst;
    int rs = (b << 10) + src;
    int pd = atomicAdd(cntd + rd, 1);
    if (pd < CAP) bucket_d[rd * CAP + pd] = tid | (src << 16);
    int ps = atomicAdd(cnts + rs, 1);
    if (ps < CAP) bucket_s[rs * CAP + ps] = dst;
}

// One wave per (b,node): float4 gather-sum of flow rows, normalize, h@W, f1, f2.
// Bucket row preloaded into registers; 8 flows (2x float4 accs) per iteration.
__global__ __launch_bounds__(256) void gather_transform_kernel(
        const float* __restrict__ ff, const int* __restrict__ cntd,
        const int* __restrict__ bucket_d, const float* __restrict__ W,
        const float* __restrict__ a1, const float* __restrict__ a2,
        float* __restrict__ Wh, float* __restrict__ f1, float* __restrict__ f2) {
    __shared__ float Ws[DD * DD];
    __shared__ float hs[4][DD];
    __shared__ float a1s[DD], a2s[DD];
    int t = threadIdx.x;
    for (int i = t; i < DD * DD / 4; i += 256)
        ((float4*)Ws)[i] = ((const float4*)W)[i];
    if (t < DD) { a1s[t] = a1[t]; a2s[t] = a2[t]; }
    int wave = t >> 6, lane = t & 63;
    int fq = lane >> 4;                         // flow slot 0..3
    int qi = lane & 15;                         // float4 index within row
    int row = blockIdx.x * 4 + wave;            // [0, BB*NN)

    int cnt = min(cntd[row], CAP);
    const int* bk = bucket_d + (size_t)row * CAP;
    int bkreg = (lane < cnt) ? bk[lane] : 0;    // whole bucket row, 1 load
    float4 v0 = make_float4(0.f, 0.f, 0.f, 0.f);
    float4 v1 = make_float4(0.f, 0.f, 0.f, 0.f);
    int lim = min(cnt, 64);
    for (int base = 0; base < lim; base += 8) {
        int fi0 = base + fq;                    // <= 59
        int fi1 = base + 4 + fq;                // <= 63
        int w0 = __shfl(bkreg, fi0, 64);
        int w1 = __shfl(bkreg, fi1, 64);
        if (fi0 < lim) {
            float4 x = ((const float4*)(ff + (size_t)(w0 & 0xFFFF) * DD))[qi];
            v0.x += x.x; v0.y += x.y; v0.z += x.z; v0.w += x.w;
        }
        if (fi1 < lim) {
            float4 x = ((const float4*)(ff + (size_t)(w1 & 0xFFFF) * DD))[qi];
            v1.x += x.x; v1.y += x.y; v1.z += x.z; v1.w += x.w;
        }
    }
    for (int base = 64; base < cnt; base += 4) { // statistically never
        int fi = base + fq;
        if (fi < cnt) {
            int flow = bk[fi] & 0xFFFF;
            float4 x = ((const float4*)(ff + (size_t)flow * DD))[qi];
            v0.x += x.x; v0.y += x.y; v0.z += x.z; v0.w += x.w;
        }
    }
    float4 v = make_float4(v0.x + v1.x, v0.y + v1.y, v0.z + v1.z, v0.w + v1.w);
    // reduce across the 4 flow slots (xor 16 then 32 sums all fq groups)
    #pragma unroll
    for (int off = 16; off <= 32; off <<= 1) {
        v.x += __shfl_xor(v.x, off, 64);
        v.y += __shfl_xor(v.y, off, 64);
        v.z += __shfl_xor(v.z, off, 64);
        v.w += __shfl_xor(v.w, off, 64);
    }
    float ssq = (fq == 0) ? (v.x*v.x + v.y*v.y + v.z*v.z + v.w*v.w) : 0.f;
    float nrm = fmaxf(sqrtf(wave_sum(ssq)), 1e-12f);
    float inv = 1.f / nrm;
    __syncthreads();                            // Ws/a1s/a2s ready
    if (fq == 0)
        ((float4*)hs[wave])[qi] = make_float4(v.x*inv, v.y*inv, v.z*inv, v.w*inv);
    float whl = 0.f;
    #pragma unroll
    for (int k = 0; k < DD; ++k)
        whl = fmaf(hs[wave][k], Ws[k * DD + lane], whl);
    Wh[row * DD + lane] = whl;
    float p1 = wave_sum(whl * a1s[lane]);
    float p2 = wave_sum(whl * a2s[lane]);
    if (lane == 0) { f1[row] = p1; f2[row] = p2; }
}

// One wave per output row i. Neighbor set = union(srcs of in-flows, dsts of
// out-flows) via per-wave LDS bitmap (same-wave DS ops are ordered -> no
// barrier). Compact ascending, softmax over neighbors only, float4 8-wide acc.
// Common case cnt<=64: scores live in one register (no second f2 gather).
__global__ __launch_bounds__(256) void attn_kernel(
        const int* __restrict__ cntd, const int* __restrict__ cnts,
        const int* __restrict__ bucket_d, const int* __restrict__ bucket_s,
        const float* __restrict__ f1, const float* __restrict__ f2,
        const float* __restrict__ Wh, float* __restrict__ out) {
    __shared__ unsigned int bms[4][MW];         // per-wave neighbor bitmap
    __shared__ int   jls[4][JCAP];              // compact ascending neighbor ids
    __shared__ float pls[4][JCAP];              // exp(e-m) per compact slot
    int t = threadIdx.x;
    int wave = t >> 6, lane = t & 63;
    int row = blockIdx.x * 4 + wave;            // [0, BB*NN)
    int b = row >> 10;
    if (lane < MW) bms[wave][lane] = 0u;
    int c1 = min(cntd[row], CAP);
    int c2 = min(cnts[row], CAP);
    const int* bd = bucket_d + (size_t)row * CAP;
    const int* bs = bucket_s + (size_t)row * CAP;
    for (int k = lane; k < c1; k += 64) {
        int cand = (bd[k] >> 16) & 0x3FF;       // src of in-flow
        atomicOr(&bms[wave][cand >> 5], 1u << (cand & 31));
    }
    for (int k = lane; k < c2; k += 64) {
        int cand = bs[k] & 0x3FF;               // dst of out-flow
        atomicOr(&bms[wave][cand >> 5], 1u << (cand & 31));
    }
    unsigned int mword = (lane < MW) ? bms[wave][lane] : 0u;
    const float* f2b = f2 + b * NN;
    const float* Whb = Wh + (size_t)(b << 10) * DD;
    float f1i = f1[row];

    // compact set bits into jls (ascending j): prefix-sum of per-word popc
    int pc = __popc(mword);
    int x = pc;
    #pragma unroll
    for (int off = 1; off < 64; off <<= 1) {
        int y = __shfl_up(x, off, 64);
        if (lane >= off) x += y;
    }
    int cnt = __shfl(x, 63, 64);                // <= c1+c2 <= 512 = JCAP always
    int o = x - pc;                             // exclusive offset
    {
        unsigned int bits = mword;
        while (bits) {
            int bidx = __ffs(bits) - 1; bits &= bits - 1;
            jls[wave][o++] = (lane << 5) + bidx;
        }
    }

    int fq = lane >> 4;                         // neighbor slot 0..3
    int qi = lane & 15;                         // float4 index within Wh row

    if (cnt > 0) {
        float lsum;
        if (cnt <= 64) {
            // one score per lane, kept in a register for both passes
            float e_reg = -INFINITY;
            if (lane < cnt) {
                int j = jls[wave][lane];
                float e = f1i + f2b[j];
                e_reg = (e >= 0.f) ? e : 0.2f * e;
            }
            float m = wave_max(e_reg);
            float p = (lane < cnt) ? __expf(e_reg - m) : 0.f;
            if (lane < cnt) pls[wave][lane] = p;
            lsum = wave_sum(p);
        } else {
            float m = -INFINITY;
            for (int k = lane; k < cnt; k += 64) {
                int j = jls[wave][k];
                float e = f1i + f2b[j];
                e = (e >= 0.f) ? e : 0.2f * e;
                m = fmaxf(m, e);
            }
            m = wave_max(m);
            float ls = 0.f;
            for (int k = lane; k < cnt; k += 64) {
                int j = jls[wave][k];
                float e = f1i + f2b[j];
                e = (e >= 0.f) ? e : 0.2f * e;
                float p = __expf(e - m);
                pls[wave][k] = p;
                ls += p;
            }
            lsum = wave_sum(ls);
        }
        // 8 neighbor rows per iteration, float4 loads, two accumulators
        float4 a0 = make_float4(0.f, 0.f, 0.f, 0.f);
        float4 a1v = make_float4(0.f, 0.f, 0.f, 0.f);
        for (int k = fq; k < cnt; k += 8) {
            int j0   = jls[wave][k];
            float p0 = pls[wave][k];
            float4 w0 = ((const float4*)(Whb + (size_t)j0 * DD))[qi];
            a0.x = fmaf(p0, w0.x, a0.x);
            a0.y = fmaf(p0, w0.y, a0.y);
            a0.z = fmaf(p0, w0.z, a0.z);
            a0.w = fmaf(p0, w0.w, a0.w);
            int k1 = k + 4;
            if (k1 < cnt) {
                int j1   = jls[wave][k1];
                float p1 = pls[wave][k1];
                float4 w1 = ((const float4*)(Whb + (size_t)j1 * DD))[qi];
                a1v.x = fmaf(p1, w1.x, a1v.x);
                a1v.y = fmaf(p1, w1.y, a1v.y);
                a1v.z = fmaf(p1, w1.z, a1v.z);
                a1v.w = fmaf(p1, w1.w, a1v.w);
            }
        }
        float4 acc = make_float4(a0.x + a1v.x, a0.y + a1v.y,
                                 a0.z + a1v.z, a0.w + a1v.w);
        #pragma unroll
        for (int off = 16; off <= 32; off <<= 1) {
            acc.x += __shfl_xor(acc.x, off, 64);
            acc.y += __shfl_xor(acc.y, off, 64);
            acc.z += __shfl_xor(acc.z, off, 64);
            acc.w += __shfl_xor(acc.w, off, 64);
        }
        if (fq == 0) {
            float inv = 1.f / lsum;
            float4 r;
            r.x = acc.x * inv; r.y = acc.y * inv;
            r.z = acc.z * inv; r.w = acc.w * inv;
            r.x = (r.x > 0.f) ? r.x : expm1f(r.x);
            r.y = (r.y > 0.f) ? r.y : expm1f(r.y);
            r.z = (r.z > 0.f) ? r.z : expm1f(r.z);
            r.w = (r.w > 0.f) ? r.w : expm1f(r.w);
            ((float4*)(out + (size_t)row * DD))[qi] = r;
        }
    } else {
        // isolated node: softmax of uniform NEG_BIG = 1/N over ALL j
        float4 acc = make_float4(0.f, 0.f, 0.f, 0.f);
        for (int k = fq; k < NN; k += 4) {
            float4 w = ((const float4*)(Whb + (size_t)k * DD))[qi];
            acc.x += w.x; acc.y += w.y; acc.z += w.z; acc.w += w.w;
        }
        #pragma unroll
        for (int off = 16; off <= 32; off <<= 1) {
            acc.x += __shfl_xor(acc.x, off, 64);
            acc.y += __shfl_xor(acc.y, off, 64);
            acc.z += __shfl_xor(acc.z, off, 64);
            acc.w += __shfl_xor(acc.w, off, 64);
        }
        if (fq == 0) {
            float4 r;
            r.x = acc.x * (1.f / NN); r.y = acc.y * (1.f / NN);
            r.z = acc.z * (1.f / NN); r.w = acc.w * (1.f / NN);
            r.x = (r.x > 0.f) ? r.x : expm1f(r.x);
            r.y = (r.y > 0.f) ? r.y : expm1f(r.y);
            r.z = (r.z > 0.f) ? r.z : expm1f(r.z);
            r.w = (r.w > 0.f) ? r.w : expm1f(r.w);
            ((float4*)(out + (size_t)row * DD))[qi] = r;
        }
    }
}

extern "C" void kernel_launch(void* const* d_in, const int* in_sizes, int n_in,
                              void* d_out, int out_size, void* d_ws, size_t ws_size,
                              hipStream_t stream) {
    const float* ff      = (const float*)d_in[0];
    const int*   src_ips = (const int*)d_in[1];
    const int*   dst_ips = (const int*)d_in[2];
    // d_in[3] flow_volumes, d_in[4] emb, d_in[5..8] MLP params: adj weights are
    // products of sigmoids => strictly positive => only the >0 mask matters.
    const float* W  = (const float*)d_in[9];
    const float* a1 = (const float*)d_in[10];
    const float* a2 = (const float*)d_in[11];
    float* out = (float*)d_out;

    char* ws = (char*)d_ws;
    int* cntd       = (int*)ws;                          // 16 KB
    int* cnts       = (int*)(ws + (16 << 10));           // 16 KB (contig w/ cntd)
    float* f1       = (float*)(ws + (32 << 10));         // 16 KB
    float* f2       = (float*)(ws + (48 << 10));         // 16 KB
    int* bucket_d   = (int*)(ws + (1 << 20));            // 4 MB
    int* bucket_s   = (int*)(ws + (5 << 20));            // 4 MB
    float* Wh       = (float*)(ws + (9 << 20));          // 1 MB

    // zero both count arrays in one contiguous 32 KB fill
    hipMemsetAsync(cntd, 0, (32 << 10), stream);

    build_kernel<<<BB * SS / 256, 256, 0, stream>>>(src_ips, dst_ips,
                                                    cntd, cnts, bucket_d, bucket_s);
    gather_transform_kernel<<<BB * NN / 4, 256, 0, stream>>>(ff, cntd, bucket_d,
                                                             W, a1, a2, Wh, f1, f2);
    attn_kernel<<<BB * NN / 4, 256, 0, stream>>>(cntd, cnts, bucket_d, bucket_s,
                                                 f1, f2, Wh, out);
}